// Round 1
// baseline (519.082 us; speedup 1.0000x reference)
//
#include <hip/hip_runtime.h>
#include <hip/hip_bf16.h>

// Palettized 3x3 VALID conv as implicit GEMM:
//   C[M=16*254*254, 64] = A[M, K=576] * B[K=576, 64],  K = (kh*3+kw)*64 + c
// Pre-kernel: dequantize weights into d_ws as pre-swizzled bf16 MFMA B-fragments.
// Main kernel: WG tile = 4 oh-rows x 64 ow x 64 O. Stage x footprint (64c x 6r x 66w)
// fp32->bf16 into LDS once, then 18 K-chunks of mfma_f32_16x16x32_bf16.

typedef __bf16 bf16x8 __attribute__((ext_vector_type(8)));
typedef float f32x4 __attribute__((ext_vector_type(4)));

union Frag {
    uint4 q;
    bf16x8 v;
};

// ---- B dequant/swizzle: Bws[s]  s = (kc*4 + nt)*64 + lane, 16B per slot.
// lane holds B[k = kc*32 + (lane>>4)*8 + j][o = nt*16 + (lane&15)], j=0..7
// with k = (kh*3+kw)*64 + c  ->  kc: r = kc>>1 fixed, c = (kc&1)*32 + (lane>>4)*8 + j.
__global__ __launch_bounds__(256) void dequant_B(
        const float* __restrict__ lut, const int* __restrict__ widx,
        uint4* __restrict__ Bws) {
    int s = blockIdx.x * 256 + threadIdx.x;   // 0..4607
    int l = s & 63;
    int nt = (s >> 6) & 3;
    int kc = s >> 8;
    if (kc >= 18) return;
    int r = kc >> 1;
    int kh = r / 3, kw = r - kh * 3;
    int o = nt * 16 + (l & 15);
    int c0 = (kc & 1) * 32 + (l >> 4) * 8;
    Frag f;
#pragma unroll
    for (int j = 0; j < 8; ++j) {
        int c = c0 + j;
        int idx = widx[((o * 64 + c) * 3 + kh) * 3 + kw];
        f.v[j] = (__bf16)lut[idx];
    }
    Bws[s] = f.q;
}

// LDS layout: ldsA[cblk][pix] as 16B granules; pix = row*66 + col (row 0..5, col 0..65)
// granule = 8 bf16 = channels cblk*8 .. cblk*8+7 of pixel (row,col).
#define LDS_PIX 396

__global__ __launch_bounds__(256, 3) void conv_mfma(
        const float* __restrict__ x, const float* __restrict__ bias,
        const uint4* __restrict__ Bws, float* __restrict__ out) {
    __shared__ uint4 ldsA[8 * LDS_PIX];   // 50688 B

    int bx = blockIdx.x;
    int ow0 = (bx & 3) * 64;          // 0,64,128,192
    int oh0 = ((bx >> 2) & 63) * 4;   // 0..252
    int n = bx >> 8;                  // 0..15
    int t = threadIdx.x;

    // ---- stage x[n, 0:64, oh0:oh0+6, ow0:ow0+66] -> LDS (fp32 -> bf16)
    {
        const float* xn = x + (size_t)n * (64 * 256 * 256);
        int col = t & 63;
        int cbb = t >> 6;   // 0..3
#pragma unroll
        for (int cp = 0; cp < 2; ++cp) {
            int cblk = cbb + cp * 4;
#pragma unroll
            for (int rr = 0; rr < 6; ++rr) {
                int y = oh0 + rr; if (y > 255) y = 255;
                const float* src = xn + cblk * 8 * 65536 + y * 256 + ow0 + col;
                Frag f;
#pragma unroll
                for (int j = 0; j < 8; ++j)
                    f.v[j] = (__bf16)src[j * 65536];
                ldsA[cblk * LDS_PIX + rr * 66 + col] = f.q;
            }
        }
        // tail: cols 64,65 (6 rows x 2 cols x 8 cblks = 96 granules)
        if (t < 96) {
            int cblk = t & 7;
            int rc = t >> 3;            // 0..11
            int rr = rc >> 1;
            int col2 = 64 + (rc & 1);
            int y = oh0 + rr; if (y > 255) y = 255;
            int xc = ow0 + col2; if (xc > 255) xc = 255;
            const float* src = xn + cblk * 8 * 65536 + y * 256 + xc;
            Frag f;
#pragma unroll
            for (int j = 0; j < 8; ++j)
                f.v[j] = (__bf16)src[j * 65536];
            ldsA[cblk * LDS_PIX + rr * 66 + col2] = f.q;
        }
    }
    __syncthreads();

    // ---- main GEMM: wave w handles oh row (oh0+w) x 64 ow x 64 O
    int w = t >> 6;
    int l = t & 63;
    int l15 = l & 15, l4 = l >> 4;

    f32x4 acc[4][4] = {};

    for (int kc = 0; kc < 18; ++kc) {
        int r = kc >> 1;
        int kh = r / 3, kw = r - kh * 3;       // block-uniform
        int cblk = (kc & 1) * 4 + l4;
        int pix = (w + kh) * 66 + l15 + kw;

        Frag b[4];
#pragma unroll
        for (int nt = 0; nt < 4; ++nt)
            b[nt].q = Bws[(kc * 4 + nt) * 64 + l];

        Frag a[4];
#pragma unroll
        for (int mt = 0; mt < 4; ++mt)
            a[mt].q = ldsA[cblk * LDS_PIX + pix + mt * 16];

#pragma unroll
        for (int mt = 0; mt < 4; ++mt)
#pragma unroll
            for (int nt = 0; nt < 4; ++nt)
                acc[mt][nt] = __builtin_amdgcn_mfma_f32_16x16x32_bf16(
                    a[mt].v, b[nt].v, acc[mt][nt], 0, 0, 0);
    }

    // ---- epilogue: C/D layout col(o)=lane&15, row(ow_l)=(lane>>4)*4+reg
    int oh = oh0 + w;
    if (oh < 254) {
#pragma unroll
        for (int nt = 0; nt < 4; ++nt) {
            int o = nt * 16 + l15;
            float bv = bias[o];
            float* obase = out + (((size_t)n * 64 + o) * 254 + oh) * 254 + ow0;
#pragma unroll
            for (int mt = 0; mt < 4; ++mt) {
#pragma unroll
                for (int rg = 0; rg < 4; ++rg) {
                    int owl = mt * 16 + l4 * 4 + rg;
                    if (ow0 + owl < 254)
                        obase[owl] = acc[mt][nt][rg] + bv;
                }
            }
        }
    }
}

extern "C" void kernel_launch(void* const* d_in, const int* in_sizes, int n_in,
                              void* d_out, int out_size, void* d_ws, size_t ws_size,
                              hipStream_t stream) {
    const float* x    = (const float*)d_in[0];
    const float* lut  = (const float*)d_in[1];
    const int*   widx = (const int*)d_in[2];
    const float* bias = (const float*)d_in[3];
    float* out = (float*)d_out;
    uint4* Bws = (uint4*)d_ws;   // needs 73728 B

    dequant_B<<<18, 256, 0, stream>>>(lut, widx, Bws);
    conv_mfma<<<4096, 256, 0, stream>>>(x, bias, (const uint4*)Bws, out);
}